// Round 19
// baseline (31.536 us; speedup 1.0000x reference)
//
#include <hip/hip_runtime.h>

// RegionProposal: decode 55296 anchors -> stable top-6000 by score -> greedy
// NMS (IoU>0.7) -> first 300 kept boxes zero-padded to [300,4] fp32.
//
// Round-19 = round-18 (30.4us) with k_mat+k_greedy merged into ONE 17-block
// kernel using the R11-proven agent-scope release/acquire handoff:
//   K1 k_scanrank (16x1024, R18-verbatim + zeroes the handoff counter):
//     single register pass over cls, sampled cutoff B1' (SRANK=133), exact
//     compact, packed u64 keys, per-block 64-candidate exact rank, decode,
//     scatter boxS/areaS.
//   K2 k_matgreedy (17x1024):
//     blocks 0-15: 512x512 lower-tri suppression bitmask (R18 k_mat compute,
//       aliased onto the greedy LDS arrays); maskG stored via agent-relaxed
//       atomics; threadfence + RELEASE fetch_add on wsMeta[2] (incremented on
//       BOTH fast and fallback paths -> no deadlock). Block 0 pre-zeroes out.
//     block 16: loads boxes to LDS (overlaps matrix compute), tid0
//       spin-ACQUIREs counter==16, loads maskG (agent-relaxed), then R18
//       greedy: wave-0 ballot fixed point, chunked remainder, exact
//       full-histogram fallback, fallback tail re-zero.
// Semantics identical to R10..R18 (absmax 0.0).
//
// Key=(fs<<32)|n: ascending == descending logit, ties by ascending index ==
// stable argsort(-sigmoid(logit)). IoU: fma-margin with exact-division
// fallback inside the +-1e-6 tie-zone -> decisions bit-identical to np.

#define ADIM 9
#define NANCH 55296
#define HWSZ 6144
#define CH_U4 1536      // HWSZ/4
#define TOT_U4 13824    // ADIM * CH_U4
#define TOPK 6000
#define OUTK 300
#define NBINS 16384
#define CAP 8192
#define SCAP 1024
#define SRANK 133       // 14336-sample rank target -> E[cs] ~ 512
#define MROWS 512
#define MW 8            // MROWS/64
#define THR 0.7f
#define NMAT 16         // matrix blocks in K2; block NMAT = greedy

typedef unsigned long long u64;
typedef unsigned int u32;

__device__ __forceinline__ u32 flipu(u32 b) {
    u32 u = (b & 0x80000000u) ? ~b : (b | 0x80000000u);
    return ~u;                       // ascending result == descending float
}

__device__ __forceinline__ bool iou_gt(float4 a, float aa, float4 b, float ba) {
    float ix = fminf(a.z, b.z) - fmaxf(a.x, b.x);
    float iy = fminf(a.w, b.w) - fmaxf(a.y, b.y);
    float inter = fmaxf(ix, 0.f) * fmaxf(iy, 0.f);
    float u = fmaxf(aa + ba - inter, 1e-12f);
    float d = __builtin_fmaf(-THR, u, inter);           // inter - 0.7*u
    if (__builtin_fabsf(d) > 1e-6f * u) return d > 0.f; // sign-safe outside tie-zone
    return inter / u > THR;                             // exact IEEE div == np
}

__device__ __forceinline__ float4 decode_box(const float* __restrict__ loc,
                                             const float* __restrict__ anc, u32 n) {
    u32 a = n % 9u, hw = n / 9u;
    float t0 = loc[(4 * a + 0) * HWSZ + hw];
    float t1 = loc[(4 * a + 1) * HWSZ + hw];
    float t2 = loc[(4 * a + 2) * HWSZ + hw];
    float t3 = loc[(4 * a + 3) * HWSZ + hw];
    float4 an = reinterpret_cast<const float4*>(anc)[n];
    float cx = t0 * an.z + an.x;
    float cy = t1 * an.w + an.y;
    float bw = expf(t2) * an.z;
    float bh = expf(t3) * an.w;
    return make_float4(fminf(fmaxf(cx - bw * 0.5f, 0.f), 1.f),
                       fminf(fmaxf(cy - bh * 0.5f, 0.f), 1.f),
                       fminf(fmaxf(cx + bw * 0.5f, 0.f), 1.f),
                       fminf(fmaxf(cy + bh * 0.5f, 0.f), 1.f));
}

__device__ __forceinline__ u64 sx64(u64 v, int m) {
    u32 lo = __shfl_xor((u32)(v & 0xffffffffu), m, 64);
    u32 hi = __shfl_xor((u32)(v >> 32), m, 64);
    return ((u64)hi << 32) | lo;
}

__device__ __forceinline__ u64 ce64(u64 v, int j, int lane, bool up) {
    u64 pv = sx64(v, j);
    u64 mn = (pv < v) ? pv : v;
    u64 mx = (pv < v) ? v : pv;
    return (((lane & j) == 0) == up) ? mn : mx;
}

__device__ __forceinline__ uint4 ld_cls4(const uint4* __restrict__ cls4, int i) {
    int ch = i / CH_U4;
    int e4 = i - ch * CH_U4;
    return cls4[(2 * ch + 1) * CH_U4 + e4];
}

__device__ __forceinline__ u32 block_scan(u32 s, int wid, int lane, u32* wsum) {
    u32 x = s;
    #pragma unroll
    for (int d = 1; d < 64; d <<= 1) {
        u32 y = __shfl_up(x, (unsigned)d, 64);
        if (lane >= d) x += y;
    }
    if (lane == 63) wsum[wid] = x;
    __syncthreads();
    if (wid == 0) {
        u32 w = (lane < 16) ? wsum[lane] : 0u;
        #pragma unroll
        for (int d = 1; d < 16; d <<= 1) {
            u32 y = __shfl_up(w, (unsigned)d, 64);
            if (lane >= d) w += y;
        }
        if (lane < 16) wsum[lane] = w;
    }
    __syncthreads();
    return x + (wid ? wsum[wid - 1] : 0u);
}

__device__ __forceinline__ u32 find_cutoff(const u32* hist, u32 thresh, int tid,
                                           int wid, int lane, u32* wsum, u32* sB) {
    u32 h[16];
    const uint4* h4 = reinterpret_cast<const uint4*>(hist);
    #pragma unroll
    for (int k = 0; k < 4; ++k) {
        uint4 v = h4[tid * 4 + k];
        h[4 * k + 0] = v.x; h[4 * k + 1] = v.y; h[4 * k + 2] = v.z; h[4 * k + 3] = v.w;
    }
    u32 s = 0;
    #pragma unroll
    for (int b = 0; b < 16; ++b) s += h[b];
    u32 incl = block_scan(s, wid, lane, wsum);
    u32 before = incl - s;
    if (before < thresh && incl >= thresh) {
        u32 run = before;
        #pragma unroll
        for (int b = 0; b < 16; ++b) {
            run += h[b];
            if (run >= thresh) { sB[0] = (u32)(tid * 16 + b); break; }
        }
    }
    __syncthreads();
    u32 r = sB[0];
    __syncthreads();
    return r;
}

// ---------------- K1: single-pass scan + rank + decode + scatter ----------------
__global__ void __launch_bounds__(1024) k_scanrank(const float* __restrict__ cls,
                                                   const float* __restrict__ loc,
                                                   const float* __restrict__ anc,
                                                   u32* __restrict__ wsMeta,
                                                   float4* __restrict__ boxS,
                                                   float* __restrict__ areaS) {
    __shared__ u32 hist[NBINS];            // 64KB
    __shared__ u64 skey[SCAP];             // 8KB packed (fs<<32|idx)
    __shared__ u32 wsum[16];
    __shared__ u32 sB[2];
    __shared__ u32 shu[2];

    const int tid = threadIdx.x;
    const int wid = tid >> 6;
    const int lane = tid & 63;
    const uint4* cls4 = reinterpret_cast<const uint4*>(cls);

    u64* h64 = (u64*)hist;
    for (int i = tid; i < NBINS / 2; i += 1024) h64[i] = 0ull;
    if (tid < 2) shu[tid] = 0;
    __syncthreads();

    // single register-resident pass; pad = -inf logit bits (0xFF800000):
    // flipu(-inf)=0xFF800000 -> bin 0x3FE0 (bottom of ranking) -> cannot
    // lower the sampled cutoff; 13824 real samples >= SRANK.
    uint4 buf[14];
    #pragma unroll
    for (int kk = 0; kk < 14; ++kk) {
        int i = kk * 1024 + tid;
        buf[kk] = (i < TOT_U4) ? ld_cls4(cls4, i)
                               : make_uint4(0xFF800000u, 0xFF800000u, 0xFF800000u, 0xFF800000u);
    }
    #pragma unroll
    for (int kk = 0; kk < 14; ++kk)
        atomicAdd(&hist[flipu(buf[kk].x) >> 18], 1u);
    __syncthreads();
    const u32 B1 = find_cutoff(hist, SRANK, tid, wid, lane, wsum, sB);
    const u32 K1 = (B1 + 1u) << 18;   // B1=16383 wraps to 0 -> cs=0 -> fallback (correct)

    u64 bm = 0;
    u32 cnt = 0;
    #pragma unroll
    for (int kk = 0; kk < 14; ++kk) {
        int i = kk * 1024 + tid;
        if (i < TOT_U4) {
            #pragma unroll
            for (int c = 0; c < 4; ++c) {
                u32 b = (c == 0) ? buf[kk].x : (c == 1) ? buf[kk].y
                      : (c == 2) ? buf[kk].z : buf[kk].w;
                if (flipu(b) < K1) {
                    cnt++;
                    bm |= 1ull << (kk * 4 + c);
                }
            }
        }
    }
    u32 incl = block_scan(cnt, wid, lane, wsum);
    u32 base = incl - cnt;
    if (tid == 1023) shu[0] = incl;
    __syncthreads();
    const u32 csRaw = shu[0];
    const u32 cs = csRaw < SCAP ? csRaw : SCAP;
    if (blockIdx.x == 0 && tid == 0) {
        wsMeta[0] = csRaw; wsMeta[1] = B1; wsMeta[2] = 0u;   // [2] = K2 handoff counter
    }
    if (csRaw > SCAP) return;               // fallback handled in K2 greedy block

    {   // gather: reload only uint4s containing candidates (L2-hot)
        u64 m = bm;
        u32 o = base;
        while (m) {
            int b = __ffsll((unsigned long long)m) - 1;
            m &= m - 1;
            int kk = b >> 2, c = b & 3;
            int i = kk * 1024 + tid;
            uint4 v = ld_cls4(cls4, i);
            u32 raw = (c == 0) ? v.x : (c == 1) ? v.y : (c == 2) ? v.z : v.w;
            int ch = i / CH_U4;
            int e4 = i - ch * CH_U4;
            u32 n = (u32)((e4 * 4 + c) * ADIM + ch);
            if (o < SCAP) skey[o] = ((u64)flipu(raw) << 32) | n;
            o++;
        }
    }
    if (tid >= (int)cs) skey[tid] = ~0ull;
    __syncthreads();

    // rank this block's 64 candidates: 16 threads/candidate x 64 u64 compares
    const int ci = blockIdx.x * 64 + (tid >> 4);
    const int p = tid & 15;
    const u64 myk = skey[ci];
    u32 r = 0;
    #pragma unroll 8
    for (int k = 0; k < 64; ++k) {
        int j = k * 16 + p;                  // 16 distinct words/wave
        r += (skey[j] < myk) ? 1u : 0u;      // exact pair-order (keys unique)
    }
    r += __shfl_xor(r, 1, 64);
    r += __shfl_xor(r, 2, 64);
    r += __shfl_xor(r, 4, 64);
    r += __shfl_xor(r, 8, 64);
    if (p == 0 && (u32)ci < csRaw) {
        float4 b = decode_box(loc, anc, (u32)myk);
        boxS[r] = b;
        areaS[r] = (b.z - b.x) * (b.w - b.y);
    }
}

// ---------------- K2: matrix (blocks 0-15) + greedy (block 16) ----------------
__global__ void __launch_bounds__(1024) k_matgreedy(const float* __restrict__ cls,
                                                    const float* __restrict__ loc,
                                                    const float* __restrict__ anc,
                                                    u32* __restrict__ wsMeta,
                                                    const float4* __restrict__ boxS,
                                                    const float* __restrict__ areaS,
                                                    u32* __restrict__ maskG32,
                                                    float4* __restrict__ out) {
    __shared__ u64 cand[CAP];              // 64KB (fallback hist/sort alias)
    __shared__ u64 smask[MROWS][MW];       // 32KB
    __shared__ float4 sbox[SCAP];          // 16KB (matrix blocks: B alias)
    __shared__ float  sarea[SCAP];         //       (matrix blocks: A alias)
    __shared__ float4 kept[OUTK];
    __shared__ float  karea[OUTK];
    __shared__ float4 cbox[64];
    __shared__ float  carea[64];
    __shared__ u64 supw[16];
    __shared__ u64 sbyp[1024];             // 8KB (matrix blocks: M32 alias)
    __shared__ u32 wsum[16];
    __shared__ u32 sB[2];
    __shared__ u32 shu[8];                 // 1:totF 4:kc 5:i0

    const int tid = threadIdx.x;
    const int wid = tid >> 6;
    const int lane = tid & 63;
    u32* hist = (u32*)cand;
    const uint4* cls4 = reinterpret_cast<const uint4*>(cls);

    const u32 csRaw = wsMeta[0];
    const u32 cs = csRaw < SCAP ? csRaw : SCAP;
    const bool fast = (csRaw <= SCAP);

    if (blockIdx.x < NMAT) {
        // ---------------- matrix block ----------------
        if (blockIdx.x == 0 && tid < OUTK)
            out[tid] = make_float4(0.f, 0.f, 0.f, 0.f);   // pre-zero before flag
        if (fast) {
            const u32 rowsv = csRaw < MROWS ? csRaw : MROWS;
            u32* M32 = (u32*)sbyp;                        // [32][16] alias
            if (tid < MROWS) { sbox[tid] = boxS[tid]; sarea[tid] = areaS[tid]; }
            if (tid < 512) M32[tid] = 0u;
            __syncthreads();
            const int rl = tid >> 5;                  // 0..31 row slot
            const int sub = tid & 31;                 // 16-col span
            const int row = blockIdx.x + 16 * rl;
            if (row < (int)rowsv) {
                const int j0 = sub * 16;
                int jmax = row < j0 + 16 ? row : j0 + 16;
                if (j0 < jmax) {
                    float4 rb = sbox[row];
                    float rba = sarea[row];
                    u32 bits = 0;
                    #pragma unroll 4
                    for (int j = j0; j < jmax; ++j)
                        if (iou_gt(rb, rba, sbox[j], sarea[j])) bits |= 1u << (j - j0);
                    if (bits) atomicOr(&M32[rl * 16 + (sub >> 1)], bits << ((sub & 1) * 16));
                }
            }
            __syncthreads();
            if (tid < 512) {
                int rl2 = tid >> 4, w = tid & 15;
                int row2 = blockIdx.x + 16 * rl2;
                __hip_atomic_store(&maskG32[row2 * 16 + w], M32[rl2 * 16 + w],
                                   __ATOMIC_RELAXED, __HIP_MEMORY_SCOPE_AGENT);
            }
        }
        __syncthreads();
        if (tid == 0) {
            __threadfence();
            __hip_atomic_fetch_add(&wsMeta[2], 1u, __ATOMIC_RELEASE, __HIP_MEMORY_SCOPE_AGENT);
        }
        return;
    }

    // ---------------- greedy block (blockIdx == NMAT) ----------------
    if (tid < 8) shu[tid] = 0;
    sbox[tid] = boxS[tid];                 // overlaps matrix compute
    sarea[tid] = areaS[tid];
    if (tid == 0) {
        u32 v;
        do { v = __hip_atomic_load(&wsMeta[2], __ATOMIC_ACQUIRE, __HIP_MEMORY_SCOPE_AGENT); }
        while (v < (u32)NMAT);
    }
    __syncthreads();
    {
        u32* sm32 = (u32*)smask;
        #pragma unroll
        for (int k = 0; k < 8; ++k)
            sm32[k * 1024 + tid] = __hip_atomic_load(&maskG32[k * 1024 + tid],
                                                     __ATOMIC_RELAXED, __HIP_MEMORY_SCOPE_AGENT);
    }
    __syncthreads();

    if (fast) {
        const u32 rowsv = cs < MROWS ? cs : MROWS;
        // greedy resolution on wave 0: bitmask ballot fixed point
        if (wid == 0) {
            u32 kc = 0, nexti0 = 0;
            u64 K[MW];
            #pragma unroll
            for (int w = 0; w < MW; ++w) K[w] = 0ull;
            #pragma unroll
            for (int cw = 0; cw < MW; ++cw) {
                u32 i0 = (u32)cw * 64u;
                if (i0 < rowsv && kc < OUTK) {
                    u32 ci = i0 + (u32)lane;
                    bool valid = ci < rowsv;
                    u64 myw[MW];
                    #pragma unroll
                    for (int w = 0; w < MW; ++w) myw[w] = valid ? smask[ci][w] : 0ull;
                    u64 supk = 0;
                    #pragma unroll
                    for (int w = 0; w < MW; ++w) supk |= myw[w] & K[w];
                    bool ia = valid && (supk == 0ull);
                    u64 inch = myw[cw] & ((1ull << lane) - 1ull);
                    u64 A = __ballot(ia ? 1 : 0);
                    for (int itx = 0; itx < 64; ++itx) {
                        bool na = ia && ((inch & A) == 0ull);
                        u64 A2 = __ballot(na ? 1 : 0);
                        if (A2 == A) break;
                        A = A2;
                    }
                    bool kp = (A >> lane) & 1;
                    u32 rank = (u32)__popcll(A & ((1ull << lane) - 1ull));
                    if (kp && kc + rank < OUTK) {
                        float4 c = sbox[ci];
                        kept[kc + rank] = c;
                        karea[kc + rank] = sarea[ci];
                        out[kc + rank] = c;
                    }
                    K[cw] = A;
                    kc += (u32)__popcll(A);
                    nexti0 = i0 + 64;
                }
            }
            if (lane == 0) {
                shu[4] = kc > OUTK ? OUTK : kc;
                shu[5] = nexti0;
            }
        }

        // chunked NMS remainder [nexti0, cs)  (dead when cs<=512)
        const u32 limit = cs;
        while (true) {
            __syncthreads();
            u32 kc = shu[4], i0 = shu[5];
            if (kc >= OUTK || i0 >= limit) break;
            u32 ci = i0 + (u32)lane;
            bool valid = ci < limit;
            float4 c = sbox[valid ? ci : 0];
            float ca = sarea[valid ? ci : 0];

            bool sup = false;
            for (u32 j = (u32)wid; j < kc; j += 16)
                sup = sup || iou_gt(c, ca, kept[j], karea[j]);
            u64 bal = __ballot(sup ? 1 : 0);
            if (lane == 0) supw[wid] = bal;

            u64 sby = 0;
            u32 smax = 4u * wid + 4u; if (smax > 63u) smax = 63u;
            for (u32 s = 4u * wid + 1u; s <= smax; ++s) {
                u32 p = ((u32)lane + s) & 63u;
                if (p < (u32)lane && (i0 + p) < limit)
                    if (iou_gt(c, ca, sbox[i0 + p], sarea[i0 + p])) sby |= (1ull << p);
            }
            sbyp[wid * 64 + lane] = sby;
            __syncthreads();

            if (wid == 0) {
                u64 sup64 = 0, sbyfull = 0;
                #pragma unroll
                for (int w = 0; w < 16; ++w) { sup64 |= supw[w]; sbyfull |= sbyp[w * 64 + lane]; }
                bool ia = valid && !((sup64 >> lane) & 1);
                u64 A = __ballot(ia ? 1 : 0);
                for (int itx = 0; itx < 64; ++itx) {
                    bool na = ia && ((sbyfull & A) == 0);
                    u64 A2 = __ballot(na ? 1 : 0);
                    if (A2 == A) break;
                    A = A2;
                }
                bool kp = (A >> lane) & 1;
                u32 rank = (u32)__popcll(A & ((1ull << lane) - 1ull));
                if (kp && kc + rank < OUTK) {
                    kept[kc + rank] = c; karea[kc + rank] = ca; out[kc + rank] = c;
                }
                if (lane == 0) {
                    u32 nk = kc + (u32)__popcll(A);
                    shu[4] = nk > OUTK ? OUTK : nk;
                    shu[5] = i0 + 64;
                }
            }
        }
    }

    // ---- Fallback: exact hist -> B2 -> compact -> bitonic 8192 -> NMS ----
    __syncthreads();
    if (shu[4] < OUTK) {
        const u32 consumed = fast ? cs : 0u;
        u64* h64 = (u64*)hist;
        for (int i = tid; i < NBINS / 2; i += 1024) h64[i] = 0ull;
        __syncthreads();
        #pragma unroll
        for (int half = 0; half < 2; ++half) {
            uint4 buf[7];
            #pragma unroll
            for (int kk = 0; kk < 7; ++kk) {
                int i = (half * 7 + kk) * 1024 + tid;
                buf[kk] = (i < TOT_U4) ? ld_cls4(cls4, i) : make_uint4(0u,0u,0u,0u);
            }
            #pragma unroll
            for (int kk = 0; kk < 7; ++kk) {
                int i = (half * 7 + kk) * 1024 + tid;
                if (i < TOT_U4) {
                    atomicAdd(&hist[flipu(buf[kk].x) >> 18], 1u);
                    atomicAdd(&hist[flipu(buf[kk].y) >> 18], 1u);
                    atomicAdd(&hist[flipu(buf[kk].z) >> 18], 1u);
                    atomicAdd(&hist[flipu(buf[kk].w) >> 18], 1u);
                }
            }
        }
        __syncthreads();
        const u32 B2 = find_cutoff(hist, TOPK, tid, wid, lane, wsum, sB);
        u64 bm2 = 0;
        u32 cnt2 = 0;
        #pragma unroll
        for (int half = 0; half < 2; ++half) {
            uint4 buf[7];
            #pragma unroll
            for (int kk = 0; kk < 7; ++kk) {
                int i = (half * 7 + kk) * 1024 + tid;
                buf[kk] = (i < TOT_U4) ? ld_cls4(cls4, i) : make_uint4(0xFFFFFFFFu,0xFFFFFFFFu,0xFFFFFFFFu,0xFFFFFFFFu);
            }
            #pragma unroll
            for (int kk = 0; kk < 7; ++kk) {
                int i = (half * 7 + kk) * 1024 + tid;
                if (i < TOT_U4) {
                    #pragma unroll
                    for (int c = 0; c < 4; ++c) {
                        u32 b = (c == 0) ? buf[kk].x : (c == 1) ? buf[kk].y
                              : (c == 2) ? buf[kk].z : buf[kk].w;
                        if ((flipu(b) >> 18) <= B2) {
                            cnt2++;
                            bm2 |= 1ull << ((half * 7 + kk) * 4 + c);
                        }
                    }
                }
            }
        }
        __syncthreads();
        for (int i = tid; i < CAP; i += 1024) cand[i] = ~0ull;
        u32 incl2 = block_scan(cnt2, wid, lane, wsum);
        u32 base2 = incl2 - cnt2;
        if (tid == 1023) shu[1] = incl2;
        __syncthreads();
        {
            u64 m2 = bm2;
            u32 o = base2;
            while (m2) {
                int b = __ffsll((unsigned long long)m2) - 1;
                m2 &= m2 - 1;
                int kk = b >> 2, c = b & 3;
                int i = kk * 1024 + tid;
                uint4 v = ld_cls4(cls4, i);
                u32 raw = (c == 0) ? v.x : (c == 1) ? v.y : (c == 2) ? v.z : v.w;
                int ch = i / CH_U4;
                int e4 = i - ch * CH_U4;
                u32 n = (u32)((e4 * 4 + c) * ADIM + ch);
                if (o < CAP) cand[o] = ((u64)flipu(raw) << 32) | n;
                o++;
            }
        }
        __syncthreads();
        const u32 totF = shu[1];
        const u32 limfb = totF < TOPK ? totF : TOPK;
        for (int seg = wid; seg < CAP / 64; seg += 16) {
            u64 v = cand[seg * 64 + lane];
            #pragma unroll
            for (int k = 2; k <= 64; k <<= 1)
                #pragma unroll
                for (int j = k >> 1; j >= 1; j >>= 1)
                    v = ce64(v, j, lane, (((seg * 64 + lane) & k) == 0));
            cand[seg * 64 + lane] = v;
        }
        __syncthreads();
        for (int k = 128; k <= CAP; k <<= 1) {
            for (int j = k >> 1; j >= 64; j >>= 1) {
                for (u32 p = (u32)tid; p < CAP / 2; p += 1024) {
                    u32 i = ((p & ~(u32)(j - 1)) << 1) | (p & (u32)(j - 1));
                    u32 l = i | (u32)j;
                    bool up = ((i & (u32)k) == 0);
                    u64 a = cand[i], b = cand[l];
                    if ((a > b) == up) { cand[i] = b; cand[l] = a; }
                }
                __syncthreads();
            }
            for (int seg = wid; seg < CAP / 64; seg += 16) {
                u64 v = cand[seg * 64 + lane];
                bool up = (((seg * 64) & k) == 0);
                #pragma unroll
                for (int j = 32; j >= 1; j >>= 1) v = ce64(v, j, lane, up);
                cand[seg * 64 + lane] = v;
            }
            __syncthreads();
        }
        if (tid == 0) shu[5] = consumed;
        while (true) {
            __syncthreads();
            u32 kc = shu[4], i0 = shu[5];
            if (kc >= OUTK || i0 >= limfb) break;
            if (wid == 0) {
                u32 ci = i0 + (u32)lane;
                u32 n = (ci < limfb) ? (u32)cand[ci] : 0u;
                float4 b = decode_box(loc, anc, n);
                cbox[lane] = b;
                carea[lane] = (b.z - b.x) * (b.w - b.y);
            }
            __syncthreads();
            u32 ci = i0 + (u32)lane;
            bool valid = ci < limfb;
            float4 c = cbox[lane];
            float ca = carea[lane];
            bool sup = false;
            for (u32 j = (u32)wid; j < kc; j += 16)
                sup = sup || iou_gt(c, ca, kept[j], karea[j]);
            u64 bal = __ballot(sup ? 1 : 0);
            if (lane == 0) supw[wid] = bal;
            u64 sby = 0;
            u32 smax = 4u * wid + 4u; if (smax > 63u) smax = 63u;
            for (u32 s = 4u * wid + 1u; s <= smax; ++s) {
                u32 p = ((u32)lane + s) & 63u;
                if (p < (u32)lane && (i0 + p) < limfb)
                    if (iou_gt(c, ca, cbox[p], carea[p])) sby |= (1ull << p);
            }
            sbyp[wid * 64 + lane] = sby;
            __syncthreads();
            if (wid == 0) {
                u64 sup64 = 0, sbyfull = 0;
                #pragma unroll
                for (int w = 0; w < 16; ++w) { sup64 |= supw[w]; sbyfull |= sbyp[w * 64 + lane]; }
                bool ia = valid && !((sup64 >> lane) & 1);
                u64 A = __ballot(ia ? 1 : 0);
                for (int itx = 0; itx < 64; ++itx) {
                    bool na = ia && ((sbyfull & A) == 0);
                    u64 A2 = __ballot(na ? 1 : 0);
                    if (A2 == A) break;
                    A = A2;
                }
                bool kp = (A >> lane) & 1;
                u32 rank = (u32)__popcll(A & ((1ull << lane) - 1ull));
                if (kp && kc + rank < OUTK) {
                    kept[kc + rank] = c; karea[kc + rank] = ca; out[kc + rank] = c;
                }
                if (lane == 0) {
                    u32 nk = kc + (u32)__popcll(A);
                    shu[4] = nk > OUTK ? OUTK : nk;
                    shu[5] = i0 + 64;
                }
            }
        }
        // fallback may keep fewer than pre-zero covers: re-zero tail
        __syncthreads();
        u32 kcF2 = shu[4];
        for (u32 r = (u32)tid; r < OUTK; r += 1024)
            if (r >= kcF2) out[r] = make_float4(0.f, 0.f, 0.f, 0.f);
    }
    // (fast path: out[r>=kc] pre-zeroed by matrix block 0)
}

extern "C" void kernel_launch(void* const* d_in, const int* in_sizes, int n_in,
                              void* d_out, int out_size, void* d_ws, size_t ws_size,
                              hipStream_t stream) {
    const float* cls = (const float*)d_in[0];   // (1, 18, 64, 96)
    const float* loc = (const float*)d_in[1];   // (1, 36, 64, 96)
    const float* anc = (const float*)d_in[2];   // (55296, 4)

    char* ws = (char*)d_ws;                     // needs 53,264 bytes
    u32*    wsMeta  = (u32*)(ws + 0);           // 16 B ([2] = handoff counter)
    float4* boxS    = (float4*)(ws + 16);       // 16384 B
    float*  areaS   = (float*)(ws + 16400);     // 4096 B
    u32*    maskG32 = (u32*)(ws + 20496);       // 32768 B

    k_scanrank <<<16, 1024, 0, stream>>>(cls, loc, anc, wsMeta, boxS, areaS);
    k_matgreedy<<<NMAT + 1, 1024, 0, stream>>>(cls, loc, anc, wsMeta, boxS, areaS,
                                               maskG32, (float4*)d_out);
}

// Round 20
// 30.171 us; speedup vs baseline: 1.0452x; 1.0452x over previous
//
#include <hip/hip_runtime.h>

// RegionProposal: decode 55296 anchors -> stable top-6000 by score -> greedy
// NMS (IoU>0.7) -> first 300 kept boxes zero-padded to [300,4] fp32.
//
// Round-20 = REVERT to round-18 (measured best: 30.4us, absmax 0.0).
// R19's intra-kernel agent-scope handoff merge regressed (31.5us): the
// cross-XCD acquire/release spin costs ~= a dispatch boundary.
//
//   K1 k_scanrank (16x1024): ONE register pass over cls (14 uint4/thread);
//     sample = .x of each (14/thread, SRANK=133 -> E[cs]~512); count from
//     registers; gather reloads only set-bit words (L2-hot); packed u64 keys;
//     rank 64 cand/block (16 thr/cand x 64 u64 compares) -> decode -> scatter.
//     Pad = -inf logit bits (0xFF800000) -> bottom of ranking (cannot lower
//     the sampled cutoff; 13824 real samples >= SRANK).
//   K2 k_mat (16x1024): 512x512 lower-tri suppression bitmask; block 0
//     pre-zeroes out[0..300).
//   K3 k_greedy (1x1024): masks+boxes -> LDS; wave-0 ballot fixed-point
//     greedy; chunked remainder; exact full-histogram fallback.
// Semantics identical to R10..R18 (absmax 0.0).
//
// Key=(fs<<32)|n: ascending == descending logit, ties by ascending index ==
// stable argsort(-sigmoid(logit)). IoU: fma-margin with exact-division
// fallback inside the +-1e-6 tie-zone -> decisions bit-identical to np.

#define ADIM 9
#define NANCH 55296
#define HWSZ 6144
#define CH_U4 1536      // HWSZ/4
#define TOT_U4 13824    // ADIM * CH_U4
#define TOPK 6000
#define OUTK 300
#define NBINS 16384
#define CAP 8192
#define SCAP 1024
#define SRANK 133       // 14336-sample rank target -> E[cs] ~ 512
#define MROWS 512
#define MW 8            // MROWS/64
#define THR 0.7f

typedef unsigned long long u64;
typedef unsigned int u32;

__device__ __forceinline__ u32 flipu(u32 b) {
    u32 u = (b & 0x80000000u) ? ~b : (b | 0x80000000u);
    return ~u;                       // ascending result == descending float
}

__device__ __forceinline__ bool iou_gt(float4 a, float aa, float4 b, float ba) {
    float ix = fminf(a.z, b.z) - fmaxf(a.x, b.x);
    float iy = fminf(a.w, b.w) - fmaxf(a.y, b.y);
    float inter = fmaxf(ix, 0.f) * fmaxf(iy, 0.f);
    float u = fmaxf(aa + ba - inter, 1e-12f);
    float d = __builtin_fmaf(-THR, u, inter);           // inter - 0.7*u
    if (__builtin_fabsf(d) > 1e-6f * u) return d > 0.f; // sign-safe outside tie-zone
    return inter / u > THR;                             // exact IEEE div == np
}

__device__ __forceinline__ float4 decode_box(const float* __restrict__ loc,
                                             const float* __restrict__ anc, u32 n) {
    u32 a = n % 9u, hw = n / 9u;
    float t0 = loc[(4 * a + 0) * HWSZ + hw];
    float t1 = loc[(4 * a + 1) * HWSZ + hw];
    float t2 = loc[(4 * a + 2) * HWSZ + hw];
    float t3 = loc[(4 * a + 3) * HWSZ + hw];
    float4 an = reinterpret_cast<const float4*>(anc)[n];
    float cx = t0 * an.z + an.x;
    float cy = t1 * an.w + an.y;
    float bw = expf(t2) * an.z;
    float bh = expf(t3) * an.w;
    return make_float4(fminf(fmaxf(cx - bw * 0.5f, 0.f), 1.f),
                       fminf(fmaxf(cy - bh * 0.5f, 0.f), 1.f),
                       fminf(fmaxf(cx + bw * 0.5f, 0.f), 1.f),
                       fminf(fmaxf(cy + bh * 0.5f, 0.f), 1.f));
}

__device__ __forceinline__ u64 sx64(u64 v, int m) {
    u32 lo = __shfl_xor((u32)(v & 0xffffffffu), m, 64);
    u32 hi = __shfl_xor((u32)(v >> 32), m, 64);
    return ((u64)hi << 32) | lo;
}

__device__ __forceinline__ u64 ce64(u64 v, int j, int lane, bool up) {
    u64 pv = sx64(v, j);
    u64 mn = (pv < v) ? pv : v;
    u64 mx = (pv < v) ? v : pv;
    return (((lane & j) == 0) == up) ? mn : mx;
}

__device__ __forceinline__ uint4 ld_cls4(const uint4* __restrict__ cls4, int i) {
    int ch = i / CH_U4;
    int e4 = i - ch * CH_U4;
    return cls4[(2 * ch + 1) * CH_U4 + e4];
}

__device__ __forceinline__ u32 block_scan(u32 s, int wid, int lane, u32* wsum) {
    u32 x = s;
    #pragma unroll
    for (int d = 1; d < 64; d <<= 1) {
        u32 y = __shfl_up(x, (unsigned)d, 64);
        if (lane >= d) x += y;
    }
    if (lane == 63) wsum[wid] = x;
    __syncthreads();
    if (wid == 0) {
        u32 w = (lane < 16) ? wsum[lane] : 0u;
        #pragma unroll
        for (int d = 1; d < 16; d <<= 1) {
            u32 y = __shfl_up(w, (unsigned)d, 64);
            if (lane >= d) w += y;
        }
        if (lane < 16) wsum[lane] = w;
    }
    __syncthreads();
    return x + (wid ? wsum[wid - 1] : 0u);
}

__device__ __forceinline__ u32 find_cutoff(const u32* hist, u32 thresh, int tid,
                                           int wid, int lane, u32* wsum, u32* sB) {
    u32 h[16];
    const uint4* h4 = reinterpret_cast<const uint4*>(hist);
    #pragma unroll
    for (int k = 0; k < 4; ++k) {
        uint4 v = h4[tid * 4 + k];
        h[4 * k + 0] = v.x; h[4 * k + 1] = v.y; h[4 * k + 2] = v.z; h[4 * k + 3] = v.w;
    }
    u32 s = 0;
    #pragma unroll
    for (int b = 0; b < 16; ++b) s += h[b];
    u32 incl = block_scan(s, wid, lane, wsum);
    u32 before = incl - s;
    if (before < thresh && incl >= thresh) {
        u32 run = before;
        #pragma unroll
        for (int b = 0; b < 16; ++b) {
            run += h[b];
            if (run >= thresh) { sB[0] = (u32)(tid * 16 + b); break; }
        }
    }
    __syncthreads();
    u32 r = sB[0];
    __syncthreads();
    return r;
}

// ---------------- K1: single-pass scan + rank + decode + scatter ----------------
__global__ void __launch_bounds__(1024) k_scanrank(const float* __restrict__ cls,
                                                   const float* __restrict__ loc,
                                                   const float* __restrict__ anc,
                                                   u32* __restrict__ wsMeta,
                                                   float4* __restrict__ boxS,
                                                   float* __restrict__ areaS) {
    __shared__ u32 hist[NBINS];            // 64KB
    __shared__ u64 skey[SCAP];             // 8KB packed (fs<<32|idx)
    __shared__ u32 wsum[16];
    __shared__ u32 sB[2];
    __shared__ u32 shu[2];

    const int tid = threadIdx.x;
    const int wid = tid >> 6;
    const int lane = tid & 63;
    const uint4* cls4 = reinterpret_cast<const uint4*>(cls);

    u64* h64 = (u64*)hist;
    for (int i = tid; i < NBINS / 2; i += 1024) h64[i] = 0ull;
    if (tid < 2) shu[tid] = 0;
    __syncthreads();

    // single register-resident pass over the class-1 plane.
    // pad = -inf logit bits (0xFF800000): flipu(-inf) = 0xFF800000 -> bin
    // 0x3FE0 (BOTTOM of the ranking) -> cannot lower the sampled cutoff;
    // 13824 real samples >= SRANK so the cutoff lands in a real bin.
    uint4 buf[14];
    #pragma unroll
    for (int kk = 0; kk < 14; ++kk) {
        int i = kk * 1024 + tid;
        buf[kk] = (i < TOT_U4) ? ld_cls4(cls4, i)
                               : make_uint4(0xFF800000u, 0xFF800000u, 0xFF800000u, 0xFF800000u);
    }
    // sampled histogram: every 4th element == .x of each uint4 (14/thread)
    #pragma unroll
    for (int kk = 0; kk < 14; ++kk)
        atomicAdd(&hist[flipu(buf[kk].x) >> 18], 1u);
    __syncthreads();
    const u32 B1 = find_cutoff(hist, SRANK, tid, wid, lane, wsum, sB);
    const u32 K1 = (B1 + 1u) << 18;   // if B1=16383 wraps to 0 -> cs=0 -> fallback (correct)

    // count + bitmask from registers
    u64 bm = 0;
    u32 cnt = 0;
    #pragma unroll
    for (int kk = 0; kk < 14; ++kk) {
        int i = kk * 1024 + tid;
        if (i < TOT_U4) {
            #pragma unroll
            for (int c = 0; c < 4; ++c) {
                u32 b = (c == 0) ? buf[kk].x : (c == 1) ? buf[kk].y
                      : (c == 2) ? buf[kk].z : buf[kk].w;
                if (flipu(b) < K1) {
                    cnt++;
                    bm |= 1ull << (kk * 4 + c);
                }
            }
        }
    }
    u32 incl = block_scan(cnt, wid, lane, wsum);
    u32 base = incl - cnt;
    if (tid == 1023) shu[0] = incl;
    __syncthreads();
    const u32 csRaw = shu[0];
    const u32 cs = csRaw < SCAP ? csRaw : SCAP;
    if (blockIdx.x == 0 && tid == 0) { wsMeta[0] = csRaw; wsMeta[1] = B1; }
    if (csRaw > SCAP) return;               // fallback handled in K3

    {   // gather: reload only uint4s containing candidates (L2-hot)
        u64 m = bm;
        u32 o = base;
        while (m) {
            int b = __ffsll((unsigned long long)m) - 1;
            m &= m - 1;
            int kk = b >> 2, c = b & 3;
            int i = kk * 1024 + tid;
            uint4 v = ld_cls4(cls4, i);
            u32 raw = (c == 0) ? v.x : (c == 1) ? v.y : (c == 2) ? v.z : v.w;
            int ch = i / CH_U4;
            int e4 = i - ch * CH_U4;
            u32 n = (u32)((e4 * 4 + c) * ADIM + ch);
            if (o < SCAP) skey[o] = ((u64)flipu(raw) << 32) | n;
            o++;
        }
    }
    if (tid >= (int)cs) skey[tid] = ~0ull;
    __syncthreads();

    // rank this block's 64 candidates: 16 threads/candidate x 64 u64 compares
    const int ci = blockIdx.x * 64 + (tid >> 4);
    const int p = tid & 15;
    const u64 myk = skey[ci];
    u32 r = 0;
    #pragma unroll 8
    for (int k = 0; k < 64; ++k) {
        int j = k * 16 + p;                  // 16 distinct words/wave
        r += (skey[j] < myk) ? 1u : 0u;      // exact pair-order (keys unique)
    }
    r += __shfl_xor(r, 1, 64);
    r += __shfl_xor(r, 2, 64);
    r += __shfl_xor(r, 4, 64);
    r += __shfl_xor(r, 8, 64);
    if (p == 0 && (u32)ci < csRaw) {
        float4 b = decode_box(loc, anc, (u32)myk);
        boxS[r] = b;
        areaS[r] = (b.z - b.x) * (b.w - b.y);
    }
}

// ---------------- K2: suppression matrix + out pre-zero ----------------
__global__ void __launch_bounds__(1024) k_mat(const u32* __restrict__ wsMeta,
                                              const float4* __restrict__ boxS,
                                              const float* __restrict__ areaS,
                                              u32* __restrict__ maskG32,
                                              float4* __restrict__ out) {
    __shared__ float4 B[MROWS];
    __shared__ float  A[MROWS];
    __shared__ u32 M32[32][16];
    const int tid = threadIdx.x;
    if (blockIdx.x == 0 && tid < OUTK)
        out[tid] = make_float4(0.f, 0.f, 0.f, 0.f);   // pre-zero (before K3 writes)
    const u32 csRaw = wsMeta[0];
    if (csRaw > SCAP) return;
    const u32 rowsv = csRaw < MROWS ? csRaw : MROWS;

    if (tid < MROWS) { B[tid] = boxS[tid]; A[tid] = areaS[tid]; }
    if (tid < 512) M32[tid >> 4][tid & 15] = 0u;
    __syncthreads();

    const int rl = tid >> 5;                  // 0..31 row slot
    const int sub = tid & 31;                 // 16-col span
    const int row = blockIdx.x + 16 * rl;     // rows == bid (mod 16)
    if (row < (int)rowsv) {
        const int j0 = sub * 16;
        int jmax = row < j0 + 16 ? row : j0 + 16;
        if (j0 < jmax) {
            float4 rb = B[row];
            float rba = A[row];
            u32 bits = 0;
            #pragma unroll 4
            for (int j = j0; j < jmax; ++j)
                if (iou_gt(rb, rba, B[j], A[j])) bits |= 1u << (j - j0);
            if (bits) atomicOr(&M32[rl][sub >> 1], bits << ((sub & 1) * 16));
        }
    }
    __syncthreads();
    if (tid < 512) {
        int rl2 = tid >> 4, w = tid & 15;
        int row2 = blockIdx.x + 16 * rl2;
        maskG32[row2 * 16 + w] = M32[rl2][w];
    }
}

// ---------------- K3: greedy + remainder + fallback ----------------
__global__ void __launch_bounds__(1024) k_greedy(const float* __restrict__ cls,
                                                 const float* __restrict__ loc,
                                                 const float* __restrict__ anc,
                                                 const u32* __restrict__ wsMeta,
                                                 const float4* __restrict__ boxS,
                                                 const float* __restrict__ areaS,
                                                 const u32* __restrict__ maskG32,
                                                 float4* __restrict__ out) {
    __shared__ u64 cand[CAP];              // 64KB (fallback hist/sort alias)
    __shared__ u64 smask[MROWS][MW];       // 32KB
    __shared__ float4 sbox[SCAP];          // 16KB
    __shared__ float  sarea[SCAP];
    __shared__ float4 kept[OUTK];
    __shared__ float  karea[OUTK];
    __shared__ float4 cbox[64];
    __shared__ float  carea[64];
    __shared__ u64 supw[16];
    __shared__ u64 sbyp[1024];
    __shared__ u32 wsum[16];
    __shared__ u32 sB[2];
    __shared__ u32 shu[8];                 // 1:totF 4:kc 5:i0

    const int tid = threadIdx.x;
    const int wid = tid >> 6;
    const int lane = tid & 63;
    u32* hist = (u32*)cand;
    const uint4* cls4 = reinterpret_cast<const uint4*>(cls);

    const u32 csRaw = wsMeta[0];
    const u32 cs = csRaw < SCAP ? csRaw : SCAP;
    const bool fast = (csRaw <= SCAP);

    if (tid < 8) shu[tid] = 0;
    sbox[tid] = boxS[tid];
    sarea[tid] = areaS[tid];
    {
        u32* sm32 = (u32*)smask;
        #pragma unroll
        for (int k = 0; k < 8; ++k) sm32[k * 1024 + tid] = maskG32[k * 1024 + tid];
    }
    __syncthreads();

    if (fast) {
        const u32 rowsv = cs < MROWS ? cs : MROWS;
        // greedy resolution on wave 0: bitmask ballot fixed point
        if (wid == 0) {
            u32 kc = 0, nexti0 = 0;
            u64 K[MW];
            #pragma unroll
            for (int w = 0; w < MW; ++w) K[w] = 0ull;
            #pragma unroll
            for (int cw = 0; cw < MW; ++cw) {
                u32 i0 = (u32)cw * 64u;
                if (i0 < rowsv && kc < OUTK) {
                    u32 ci = i0 + (u32)lane;
                    bool valid = ci < rowsv;
                    u64 myw[MW];
                    #pragma unroll
                    for (int w = 0; w < MW; ++w) myw[w] = valid ? smask[ci][w] : 0ull;
                    u64 supk = 0;
                    #pragma unroll
                    for (int w = 0; w < MW; ++w) supk |= myw[w] & K[w];
                    bool ia = valid && (supk == 0ull);
                    u64 inch = myw[cw] & ((1ull << lane) - 1ull);
                    u64 A = __ballot(ia ? 1 : 0);
                    for (int itx = 0; itx < 64; ++itx) {
                        bool na = ia && ((inch & A) == 0ull);
                        u64 A2 = __ballot(na ? 1 : 0);
                        if (A2 == A) break;
                        A = A2;
                    }
                    bool kp = (A >> lane) & 1;
                    u32 rank = (u32)__popcll(A & ((1ull << lane) - 1ull));
                    if (kp && kc + rank < OUTK) {
                        float4 c = sbox[ci];
                        kept[kc + rank] = c;
                        karea[kc + rank] = sarea[ci];
                        out[kc + rank] = c;
                    }
                    K[cw] = A;
                    kc += (u32)__popcll(A);
                    nexti0 = i0 + 64;
                }
            }
            if (lane == 0) {
                shu[4] = kc > OUTK ? OUTK : kc;
                shu[5] = nexti0;
            }
        }

        // chunked NMS remainder [nexti0, cs)  (dead when cs<=512)
        const u32 limit = cs;
        while (true) {
            __syncthreads();
            u32 kc = shu[4], i0 = shu[5];
            if (kc >= OUTK || i0 >= limit) break;
            u32 ci = i0 + (u32)lane;
            bool valid = ci < limit;
            float4 c = sbox[valid ? ci : 0];
            float ca = sarea[valid ? ci : 0];

            bool sup = false;
            for (u32 j = (u32)wid; j < kc; j += 16)
                sup = sup || iou_gt(c, ca, kept[j], karea[j]);
            u64 bal = __ballot(sup ? 1 : 0);
            if (lane == 0) supw[wid] = bal;

            u64 sby = 0;
            u32 smax = 4u * wid + 4u; if (smax > 63u) smax = 63u;
            for (u32 s = 4u * wid + 1u; s <= smax; ++s) {
                u32 p = ((u32)lane + s) & 63u;
                if (p < (u32)lane && (i0 + p) < limit)
                    if (iou_gt(c, ca, sbox[i0 + p], sarea[i0 + p])) sby |= (1ull << p);
            }
            sbyp[wid * 64 + lane] = sby;
            __syncthreads();

            if (wid == 0) {
                u64 sup64 = 0, sbyfull = 0;
                #pragma unroll
                for (int w = 0; w < 16; ++w) { sup64 |= supw[w]; sbyfull |= sbyp[w * 64 + lane]; }
                bool ia = valid && !((sup64 >> lane) & 1);
                u64 A = __ballot(ia ? 1 : 0);
                for (int itx = 0; itx < 64; ++itx) {
                    bool na = ia && ((sbyfull & A) == 0);
                    u64 A2 = __ballot(na ? 1 : 0);
                    if (A2 == A) break;
                    A = A2;
                }
                bool kp = (A >> lane) & 1;
                u32 rank = (u32)__popcll(A & ((1ull << lane) - 1ull));
                if (kp && kc + rank < OUTK) {
                    kept[kc + rank] = c; karea[kc + rank] = ca; out[kc + rank] = c;
                }
                if (lane == 0) {
                    u32 nk = kc + (u32)__popcll(A);
                    shu[4] = nk > OUTK ? OUTK : nk;
                    shu[5] = i0 + 64;
                }
            }
        }
    }

    // ---- Fallback: exact hist -> B2 -> compact -> bitonic 8192 -> NMS ----
    __syncthreads();
    if (shu[4] < OUTK) {
        const u32 consumed = fast ? cs : 0u;
        u64* h64 = (u64*)hist;
        for (int i = tid; i < NBINS / 2; i += 1024) h64[i] = 0ull;
        __syncthreads();
        #pragma unroll
        for (int half = 0; half < 2; ++half) {
            uint4 buf[7];
            #pragma unroll
            for (int kk = 0; kk < 7; ++kk) {
                int i = (half * 7 + kk) * 1024 + tid;
                buf[kk] = (i < TOT_U4) ? ld_cls4(cls4, i) : make_uint4(0u,0u,0u,0u);
            }
            #pragma unroll
            for (int kk = 0; kk < 7; ++kk) {
                int i = (half * 7 + kk) * 1024 + tid;
                if (i < TOT_U4) {
                    atomicAdd(&hist[flipu(buf[kk].x) >> 18], 1u);
                    atomicAdd(&hist[flipu(buf[kk].y) >> 18], 1u);
                    atomicAdd(&hist[flipu(buf[kk].z) >> 18], 1u);
                    atomicAdd(&hist[flipu(buf[kk].w) >> 18], 1u);
                }
            }
        }
        __syncthreads();
        const u32 B2 = find_cutoff(hist, TOPK, tid, wid, lane, wsum, sB);
        u64 bm2 = 0;
        u32 cnt2 = 0;
        #pragma unroll
        for (int half = 0; half < 2; ++half) {
            uint4 buf[7];
            #pragma unroll
            for (int kk = 0; kk < 7; ++kk) {
                int i = (half * 7 + kk) * 1024 + tid;
                buf[kk] = (i < TOT_U4) ? ld_cls4(cls4, i) : make_uint4(0xFFFFFFFFu,0xFFFFFFFFu,0xFFFFFFFFu,0xFFFFFFFFu);
            }
            #pragma unroll
            for (int kk = 0; kk < 7; ++kk) {
                int i = (half * 7 + kk) * 1024 + tid;
                if (i < TOT_U4) {
                    #pragma unroll
                    for (int c = 0; c < 4; ++c) {
                        u32 b = (c == 0) ? buf[kk].x : (c == 1) ? buf[kk].y
                              : (c == 2) ? buf[kk].z : buf[kk].w;
                        if ((flipu(b) >> 18) <= B2) {
                            cnt2++;
                            bm2 |= 1ull << ((half * 7 + kk) * 4 + c);
                        }
                    }
                }
            }
        }
        __syncthreads();
        for (int i = tid; i < CAP; i += 1024) cand[i] = ~0ull;
        u32 incl2 = block_scan(cnt2, wid, lane, wsum);
        u32 base2 = incl2 - cnt2;
        if (tid == 1023) shu[1] = incl2;
        __syncthreads();
        {
            u64 m2 = bm2;
            u32 o = base2;
            while (m2) {
                int b = __ffsll((unsigned long long)m2) - 1;
                m2 &= m2 - 1;
                int kk = b >> 2, c = b & 3;
                int i = kk * 1024 + tid;
                uint4 v = ld_cls4(cls4, i);
                u32 raw = (c == 0) ? v.x : (c == 1) ? v.y : (c == 2) ? v.z : v.w;
                int ch = i / CH_U4;
                int e4 = i - ch * CH_U4;
                u32 n = (u32)((e4 * 4 + c) * ADIM + ch);
                if (o < CAP) cand[o] = ((u64)flipu(raw) << 32) | n;
                o++;
            }
        }
        __syncthreads();
        const u32 totF = shu[1];
        const u32 limfb = totF < TOPK ? totF : TOPK;
        for (int seg = wid; seg < CAP / 64; seg += 16) {
            u64 v = cand[seg * 64 + lane];
            #pragma unroll
            for (int k = 2; k <= 64; k <<= 1)
                #pragma unroll
                for (int j = k >> 1; j >= 1; j >>= 1)
                    v = ce64(v, j, lane, (((seg * 64 + lane) & k) == 0));
            cand[seg * 64 + lane] = v;
        }
        __syncthreads();
        for (int k = 128; k <= CAP; k <<= 1) {
            for (int j = k >> 1; j >= 64; j >>= 1) {
                for (u32 p = (u32)tid; p < CAP / 2; p += 1024) {
                    u32 i = ((p & ~(u32)(j - 1)) << 1) | (p & (u32)(j - 1));
                    u32 l = i | (u32)j;
                    bool up = ((i & (u32)k) == 0);
                    u64 a = cand[i], b = cand[l];
                    if ((a > b) == up) { cand[i] = b; cand[l] = a; }
                }
                __syncthreads();
            }
            for (int seg = wid; seg < CAP / 64; seg += 16) {
                u64 v = cand[seg * 64 + lane];
                bool up = (((seg * 64) & k) == 0);
                #pragma unroll
                for (int j = 32; j >= 1; j >>= 1) v = ce64(v, j, lane, up);
                cand[seg * 64 + lane] = v;
            }
            __syncthreads();
        }
        if (tid == 0) shu[5] = consumed;
        while (true) {
            __syncthreads();
            u32 kc = shu[4], i0 = shu[5];
            if (kc >= OUTK || i0 >= limfb) break;
            if (wid == 0) {
                u32 ci = i0 + (u32)lane;
                u32 n = (ci < limfb) ? (u32)cand[ci] : 0u;
                float4 b = decode_box(loc, anc, n);
                cbox[lane] = b;
                carea[lane] = (b.z - b.x) * (b.w - b.y);
            }
            __syncthreads();
            u32 ci = i0 + (u32)lane;
            bool valid = ci < limfb;
            float4 c = cbox[lane];
            float ca = carea[lane];
            bool sup = false;
            for (u32 j = (u32)wid; j < kc; j += 16)
                sup = sup || iou_gt(c, ca, kept[j], karea[j]);
            u64 bal = __ballot(sup ? 1 : 0);
            if (lane == 0) supw[wid] = bal;
            u64 sby = 0;
            u32 smax = 4u * wid + 4u; if (smax > 63u) smax = 63u;
            for (u32 s = 4u * wid + 1u; s <= smax; ++s) {
                u32 p = ((u32)lane + s) & 63u;
                if (p < (u32)lane && (i0 + p) < limfb)
                    if (iou_gt(c, ca, cbox[p], carea[p])) sby |= (1ull << p);
            }
            sbyp[wid * 64 + lane] = sby;
            __syncthreads();
            if (wid == 0) {
                u64 sup64 = 0, sbyfull = 0;
                #pragma unroll
                for (int w = 0; w < 16; ++w) { sup64 |= supw[w]; sbyfull |= sbyp[w * 64 + lane]; }
                bool ia = valid && !((sup64 >> lane) & 1);
                u64 A = __ballot(ia ? 1 : 0);
                for (int itx = 0; itx < 64; ++itx) {
                    bool na = ia && ((sbyfull & A) == 0);
                    u64 A2 = __ballot(na ? 1 : 0);
                    if (A2 == A) break;
                    A = A2;
                }
                bool kp = (A >> lane) & 1;
                u32 rank = (u32)__popcll(A & ((1ull << lane) - 1ull));
                if (kp && kc + rank < OUTK) {
                    kept[kc + rank] = c; karea[kc + rank] = ca; out[kc + rank] = c;
                }
                if (lane == 0) {
                    u32 nk = kc + (u32)__popcll(A);
                    shu[4] = nk > OUTK ? OUTK : nk;
                    shu[5] = i0 + 64;
                }
            }
        }
        // fallback may keep fewer than the pre-zeroed region covers: re-zero tail
        __syncthreads();
        u32 kcF2 = shu[4];
        for (u32 r = (u32)tid; r < OUTK; r += 1024)
            if (r >= kcF2) out[r] = make_float4(0.f, 0.f, 0.f, 0.f);
    }
    // (fast path: out[r>=kc] pre-zeroed by k_mat block 0)
}

extern "C" void kernel_launch(void* const* d_in, const int* in_sizes, int n_in,
                              void* d_out, int out_size, void* d_ws, size_t ws_size,
                              hipStream_t stream) {
    const float* cls = (const float*)d_in[0];   // (1, 18, 64, 96)
    const float* loc = (const float*)d_in[1];   // (1, 36, 64, 96)
    const float* anc = (const float*)d_in[2];   // (55296, 4)

    char* ws = (char*)d_ws;                     // needs 53,264 bytes
    u32*    wsMeta  = (u32*)(ws + 0);           // 16 B
    float4* boxS    = (float4*)(ws + 16);       // 16384 B
    float*  areaS   = (float*)(ws + 16400);     // 4096 B
    u32*    maskG32 = (u32*)(ws + 20496);       // 32768 B

    k_scanrank<<<16, 1024, 0, stream>>>(cls, loc, anc, wsMeta, boxS, areaS);
    k_mat     <<<16, 1024, 0, stream>>>(wsMeta, boxS, areaS, maskG32, (float4*)d_out);
    k_greedy  <<<1, 1024, 0, stream>>>(cls, loc, anc, wsMeta, boxS, areaS, maskG32, (float4*)d_out);
}